// Round 1
// baseline (320.710 us; speedup 1.0000x reference)
//
#include <hip/hip_runtime.h>
#include <hip/hip_bf16.h>

#define B_   4
#define N_   2048
#define IN_  256
#define OUT_ 256
#define H_   4
#define HD_  64
#define LN_EPS 1e-5f

typedef __bf16 bf16x8 __attribute__((ext_vector_type(8)));
typedef float  f32x4  __attribute__((ext_vector_type(4)));
typedef unsigned short u16x8 __attribute__((ext_vector_type(8)));

__device__ __forceinline__ unsigned short f2bf(float x) {
    unsigned int u = __float_as_uint(x);
    return (unsigned short)((u + 0x7FFFu + ((u >> 16) & 1u)) >> 16);
}

// ---------------------------------------------------------------------------
// Phase A: X = lrelu(nf@W_lin + b), q = lrelu(nf@W_q), k = lrelu(nf@W_k)
// q,k stored row-major bf16 [B*N][256]; X stored transposed bf16 [B][H][64][N]
// ---------------------------------------------------------------------------
__global__ __launch_bounds__(256) void gemm3_kernel(
    const float* __restrict__ nf, const float* __restrict__ Wl,
    const float* __restrict__ bl, const float* __restrict__ Wq,
    const float* __restrict__ Wk,
    unsigned short* __restrict__ qb, unsigned short* __restrict__ kb,
    unsigned short* __restrict__ Xt)
{
    const int z  = blockIdx.z;                 // 0: X, 1: q, 2: k
    const float* W = (z == 0) ? Wl : (z == 1 ? Wq : Wk);
    const int m0 = blockIdx.x * 64;
    const int n0 = blockIdx.y * 64;
    const int tid  = threadIdx.x;
    const int wave = tid >> 6;
    const int lane = tid & 63;
    const int lq = lane >> 4, lr = lane & 15;

    __shared__ unsigned short As[64][40];   // 64 rows x 32 k (pad to 40)
    __shared__ unsigned short Bt[64][40];   // 64 cols x 32 k (W transposed)

    f32x4 acc[4] = {};

    for (int k0 = 0; k0 < IN_; k0 += 32) {
        // stage A tile: thread t -> row t/4, 8 floats at (t%4)*8
        {
            int r = tid >> 2, c = (tid & 3) * 8;
            const float* src = nf + (size_t)(m0 + r) * IN_ + k0 + c;
            u16x8 v;
            #pragma unroll
            for (int j = 0; j < 8; j++) v[j] = f2bf(src[j]);
            *(u16x8*)&As[r][c] = v;
        }
        // stage W tile transposed: thread t -> k row t/8, 8 cols at (t%8)*8
        {
            int kk = tid >> 3, c0 = (tid & 7) * 8;
            const float* src = W + (size_t)(k0 + kk) * OUT_ + n0 + c0;
            #pragma unroll
            for (int j = 0; j < 8; j++) Bt[c0 + j][kk] = f2bf(src[j]);
        }
        __syncthreads();

        bf16x8 af = *(const bf16x8*)&As[wave * 16 + lr][lq * 8];
        #pragma unroll
        for (int f = 0; f < 4; f++) {
            bf16x8 bfr = *(const bf16x8*)&Bt[f * 16 + lr][lq * 8];
            acc[f] = __builtin_amdgcn_mfma_f32_16x16x32_bf16(af, bfr, acc[f], 0, 0, 0);
        }
        __syncthreads();
    }

    // epilogue: bias (z==0), leaky relu, cast bf16, store
    #pragma unroll
    for (int f = 0; f < 4; f++) {
        int c = n0 + f * 16 + lr;
        float bias = (z == 0) ? bl[c] : 0.0f;
        #pragma unroll
        for (int r = 0; r < 4; r++) {
            int m = m0 + wave * 16 + lq * 4 + r;
            float v = acc[f][r] + bias;
            v = (v >= 0.f) ? v : 0.01f * v;
            unsigned short bv = f2bf(v);
            if (z == 0) {
                int n = m & (N_ - 1);
                int h = c >> 6, d = c & 63;
                Xt[(((size_t)(m >> 11) * H_ + h) * HD_ + d) * N_ + n] = bv;
            } else {
                unsigned short* dst = (z == 1) ? qb : kb;
                dst[(size_t)m * OUT_ + c] = bv;
            }
        }
    }
}

// ---------------------------------------------------------------------------
// Phase B: deg[b,h,x] = sum_y adj[b,x,y]*sigmoid(q.k/8);  dis = deg^-1/2
// block: 16 x-rows, 4 waves = 4 heads; loop y in tiles of 64
// ---------------------------------------------------------------------------
__global__ __launch_bounds__(256) void deg_kernel(
    const float* __restrict__ adj,
    const unsigned short* __restrict__ qb,
    const unsigned short* __restrict__ kb,
    float* __restrict__ dis)
{
    const int b  = blockIdx.y;
    const int x0 = blockIdx.x * 16;
    const int h    = threadIdx.x >> 6;
    const int lane = threadIdx.x & 63;
    const int lq = lane >> 4, lr = lane & 15;
    const float sc = -0.125f * 1.44269504088896f;   // sigmoid via exp2

    bf16x8 qf[2];
    #pragma unroll
    for (int ks = 0; ks < 2; ks++)
        qf[ks] = *(const bf16x8*)&qb[(size_t)(b * N_ + x0 + lr) * OUT_ + h * HD_ + ks * 32 + lq * 8];

    float degp[4] = {0.f, 0.f, 0.f, 0.f};

    for (int yt = 0; yt < N_ / 64; yt++) {
        const int y0 = yt * 64;
        f32x4 S[4] = {};
        #pragma unroll
        for (int yb = 0; yb < 4; yb++) {
            #pragma unroll
            for (int ks = 0; ks < 2; ks++) {
                bf16x8 kf = *(const bf16x8*)&kb[(size_t)(b * N_ + y0 + yb * 16 + lr) * OUT_ + h * HD_ + ks * 32 + lq * 8];
                S[yb] = __builtin_amdgcn_mfma_f32_16x16x32_bf16(qf[ks], kf, S[yb], 0, 0, 0);
            }
        }
        #pragma unroll
        for (int yb = 0; yb < 4; yb++) {
            #pragma unroll
            for (int r = 0; r < 4; r++) {
                int x = x0 + lq * 4 + r;
                int y = y0 + yb * 16 + lr;
                float a = adj[((size_t)b * N_ + x) * N_ + y];
                float att = __builtin_amdgcn_rcpf(1.f + exp2f(S[yb][r] * sc));
                degp[r] += a * att;
            }
        }
    }
    #pragma unroll
    for (int r = 0; r < 4; r++) {
        float v = degp[r];
        v += __shfl_xor(v, 1); v += __shfl_xor(v, 2);
        v += __shfl_xor(v, 4); v += __shfl_xor(v, 8);
        degp[r] = v;
    }
    if (lr == 0) {
        #pragma unroll
        for (int r = 0; r < 4; r++) {
            int x = x0 + lq * 4 + r;
            float d = degp[r];
            dis[((size_t)b * H_ + h) * N_ + x] = (d > 0.f) ? rsqrtf(d) : 0.f;
        }
    }
}

// ---------------------------------------------------------------------------
// Phase D: Y = dis_x * sum_y (adj*att*dis_y) * X[y];  then LayerNorm
// block: 16 x-rows, 4 waves = 4 heads
// ---------------------------------------------------------------------------
__global__ __launch_bounds__(256) void out_kernel(
    const float* __restrict__ adj,
    const unsigned short* __restrict__ qb,
    const unsigned short* __restrict__ kb,
    const unsigned short* __restrict__ Xt,
    const float* __restrict__ dis,
    const float* __restrict__ ln_g,
    const float* __restrict__ ln_b,
    float* __restrict__ out)
{
    const int b  = blockIdx.y;
    const int x0 = blockIdx.x * 16;
    const int h    = threadIdx.x >> 6;
    const int lane = threadIdx.x & 63;
    const int lq = lane >> 4, lr = lane & 15;
    const float sc = -0.125f * 1.44269504088896f;

    __shared__ unsigned short wls[4][16][72];   // per-wave private w tile
    __shared__ float lnred[2][4][16];

    bf16x8 qf[2];
    #pragma unroll
    for (int ks = 0; ks < 2; ks++)
        qf[ks] = *(const bf16x8*)&qb[(size_t)(b * N_ + x0 + lr) * OUT_ + h * HD_ + ks * 32 + lq * 8];

    float dx[4];
    #pragma unroll
    for (int r = 0; r < 4; r++)
        dx[r] = dis[((size_t)b * H_ + h) * N_ + x0 + lq * 4 + r];

    f32x4 Y[4] = {};

    for (int yt = 0; yt < N_ / 64; yt++) {
        const int y0 = yt * 64;
        f32x4 S[4] = {};
        #pragma unroll
        for (int yb = 0; yb < 4; yb++) {
            #pragma unroll
            for (int ks = 0; ks < 2; ks++) {
                bf16x8 kf = *(const bf16x8*)&kb[(size_t)(b * N_ + y0 + yb * 16 + lr) * OUT_ + h * HD_ + ks * 32 + lq * 8];
                S[yb] = __builtin_amdgcn_mfma_f32_16x16x32_bf16(qf[ks], kf, S[yb], 0, 0, 0);
            }
        }
        // w = adj * sigmoid * dis_y  -> per-wave LDS tile (bf16)
        #pragma unroll
        for (int yb = 0; yb < 4; yb++) {
            float dy = dis[((size_t)b * H_ + h) * N_ + y0 + yb * 16 + lr];
            #pragma unroll
            for (int r = 0; r < 4; r++) {
                int x = x0 + lq * 4 + r;
                int y = y0 + yb * 16 + lr;
                float a = adj[((size_t)b * N_ + x) * N_ + y];
                float att = __builtin_amdgcn_rcpf(1.f + exp2f(S[yb][r] * sc));
                wls[h][lq * 4 + r][yb * 16 + lr] = f2bf(a * att * dy);
            }
        }
        // PV: Y[16x][64d] += w[16x][64y] @ X[64y][64d]  (no barrier: wave-private LDS)
        #pragma unroll
        for (int ks = 0; ks < 2; ks++) {
            bf16x8 wf = *(const bf16x8*)&wls[h][lr][ks * 32 + lq * 8];
            #pragma unroll
            for (int db = 0; db < 4; db++) {
                bf16x8 xf = *(const bf16x8*)&Xt[(((size_t)b * H_ + h) * HD_ + db * 16 + lr) * N_ + y0 + ks * 32 + lq * 8];
                Y[db] = __builtin_amdgcn_mfma_f32_16x16x32_bf16(wf, xf, Y[db], 0, 0, 0);
            }
        }
    }

    // epilogue: scale by dis_x, LayerNorm over 256 cols (4 waves x 64)
    float s1[4] = {}, s2[4] = {};
    #pragma unroll
    for (int r = 0; r < 4; r++) {
        #pragma unroll
        for (int db = 0; db < 4; db++) {
            float v = Y[db][r] * dx[r];
            s1[r] += v; s2[r] += v * v;
        }
    }
    #pragma unroll
    for (int r = 0; r < 4; r++) {
        float a = s1[r], q2 = s2[r];
        a += __shfl_xor(a, 1); a += __shfl_xor(a, 2); a += __shfl_xor(a, 4); a += __shfl_xor(a, 8);
        q2 += __shfl_xor(q2, 1); q2 += __shfl_xor(q2, 2); q2 += __shfl_xor(q2, 4); q2 += __shfl_xor(q2, 8);
        s1[r] = a; s2[r] = q2;
    }
    if (lr == 0) {
        #pragma unroll
        for (int r = 0; r < 4; r++) {
            lnred[0][h][lq * 4 + r] = s1[r];
            lnred[1][h][lq * 4 + r] = s2[r];
        }
    }
    __syncthreads();

    float gg[4], bb[4];
    #pragma unroll
    for (int db = 0; db < 4; db++) {
        int c = h * HD_ + db * 16 + lr;
        gg[db] = ln_g[c]; bb[db] = ln_b[c];
    }
    #pragma unroll
    for (int r = 0; r < 4; r++) {
        int xr = lq * 4 + r;
        float t1 = lnred[0][0][xr] + lnred[0][1][xr] + lnred[0][2][xr] + lnred[0][3][xr];
        float t2 = lnred[1][0][xr] + lnred[1][1][xr] + lnred[1][2][xr] + lnred[1][3][xr];
        float mu  = t1 * (1.f / 256.f);
        float var = t2 * (1.f / 256.f) - mu * mu;
        float rs  = rsqrtf(var + LN_EPS);
        #pragma unroll
        for (int db = 0; db < 4; db++) {
            int c = h * HD_ + db * 16 + lr;
            float v = (Y[db][r] * dx[r] - mu) * rs * gg[db] + bb[db];
            out[((size_t)(b * N_ + x0 + xr)) * OUT_ + c] = v;
        }
    }
}

extern "C" void kernel_launch(void* const* d_in, const int* in_sizes, int n_in,
                              void* d_out, int out_size, void* d_ws, size_t ws_size,
                              hipStream_t stream) {
    const float* nf  = (const float*)d_in[0];
    const float* adj = (const float*)d_in[1];
    const float* Wl  = (const float*)d_in[2];
    const float* bl  = (const float*)d_in[3];
    const float* Wq  = (const float*)d_in[4];
    const float* Wk  = (const float*)d_in[5];
    const float* lng = (const float*)d_in[6];
    const float* lnb = (const float*)d_in[7];
    float* out = (float*)d_out;

    unsigned short* qb = (unsigned short*)d_ws;                 // 4 MB
    unsigned short* kb = qb + (size_t)B_ * N_ * OUT_;           // 4 MB
    unsigned short* Xt = kb + (size_t)B_ * N_ * OUT_;           // 4 MB
    float*         dis = (float*)(Xt + (size_t)B_ * N_ * OUT_); // 128 KB

    gemm3_kernel<<<dim3(128, 4, 3), 256, 0, stream>>>(nf, Wl, bl, Wq, Wk, qb, kb, Xt);
    deg_kernel<<<dim3(N_ / 16, B_), 256, 0, stream>>>(adj, qb, kb, dis);
    out_kernel<<<dim3(N_ / 16, B_), 256, 0, stream>>>(adj, qb, kb, Xt, dis, lng, lnb, out);
}